// Round 1
// baseline (1328.500 us; speedup 1.0000x reference)
//
#include <hip/hip_runtime.h>
#include <stdint.h>

typedef __attribute__((ext_vector_type(8))) short short8;
typedef __attribute__((ext_vector_type(8))) unsigned short ushort8;
typedef __attribute__((ext_vector_type(4))) float f32x4;

#define MFMA(a,b,c) __builtin_amdgcn_mfma_f32_16x16x32_bf16((a),(b),(c),0,0,0)

__device__ __forceinline__ unsigned short f2bf(float f) {
  union { float f; unsigned u; } v; v.f = f;
  unsigned r = v.u + 0x7fffu + ((v.u >> 16) & 1u);
  return (unsigned short)(r >> 16);
}

// V LDS swizzle: row c (128B = 32 banks), spread keys by high-and-low c bits.
__device__ __forceinline__ int vswz(int c, int key) {
  return key ^ ((((c >> 3) ^ c) & 7) << 3);
}

// ---------------- prep: fold BN into 1x1 weights, attn scale into q rows ----
__global__ void fold_qvk_kernel(const float* __restrict__ qv_w, const float* __restrict__ qv_b,
                                const float* __restrict__ k_w, const float* __restrict__ k_b,
                                const float* __restrict__ g, const float* __restrict__ be,
                                const float* __restrict__ mu, const float* __restrict__ var,
                                unsigned short* __restrict__ Wq, float* __restrict__ bq,
                                unsigned short* __restrict__ Wk, float* __restrict__ bk) {
  int o = blockIdx.x;            // 0..767 -> qv row, 768..1151 -> k row
  int t = threadIdx.x;           // 128
  bool isq = o < 768;
  int oo = isq ? o : o - 768;
  const float* wrow = isq ? qv_w + (size_t)oo * 384 : k_w + (size_t)oo * 384;
  float mul = (isq && oo < 384) ? 0.08838834764831845f : 1.0f;  // 1/sqrt(128) folded into q
  float acc = 0.f;
  for (int c = t; c < 384; c += 128) {
    float sc = g[c] * rsqrtf(var[c] + 1e-5f);
    float sh = be[c] - mu[c] * sc;
    float w = wrow[c];
    acc += w * sh;
    unsigned short wb = f2bf(w * sc * mul);
    if (isq) Wq[(size_t)oo * 384 + c] = wb; else Wk[(size_t)oo * 384 + c] = wb;
  }
#pragma unroll
  for (int m = 1; m < 64; m <<= 1) acc += __shfl_xor(acc, m);
  __shared__ float part[2];
  if ((t & 63) == 0) part[t >> 6] = acc;
  __syncthreads();
  if (t == 0) {
    float b0 = isq ? qv_b[oo] : k_b[oo];
    float bias = (b0 + part[0] + part[1]) * mul;
    if (isq) bq[oo] = bias; else bk[oo] = bias;
  }
}

// reorder oc_w (o,c,kh,kw) -> Wc[o][kq][c] bf16 ; compute output-BN scale/shift
__global__ void fold_oc_kernel(const float* __restrict__ oc_w,
                               const float* __restrict__ g, const float* __restrict__ be,
                               const float* __restrict__ mu, const float* __restrict__ var,
                               unsigned short* __restrict__ Wc, float* __restrict__ s_oc,
                               float* __restrict__ t_oc) {
  int idx = blockIdx.x * 256 + threadIdx.x;
  if (idx < 384) {
    float sc = g[idx] * rsqrtf(var[idx] + 1e-5f);
    s_oc[idx] = sc;
    t_oc[idx] = be[idx] - mu[idx] * sc;
  }
  if (idx < 384 * 3456) {
    int o = idx / 3456, r = idx % 3456;
    int kq = r / 384, c = r % 384;
    Wc[idx] = f2bf(oc_w[((size_t)o * 384 + c) * 9 + kq]);
  }
}

// ---------------- GEMM-1: out[b][p][o] = sum_c W[o][c] * X[b][c][p] + bias --
// A-operand = X (p x c) from Bs, B-operand = W^T (c x o) from As; D[p][o].
__launch_bounds__(256)
__global__ void gemm1_kernel(const float* __restrict__ X, const unsigned short* __restrict__ W,
                             const float* __restrict__ bias, unsigned short* __restrict__ Out,
                             int OW, int OT) {
  int bi = blockIdx.x;
  int ot = bi % OT;
  int pt = (bi / OT) % 288;
  int bb = bi / (OT * 288);
  int obase = ot * 128, pbase = pt * 128;
  __shared__ unsigned short As[128 * 40];  // W rows [o][c], pad 40
  __shared__ unsigned short Bs[128 * 40];  // X rows [p][c]
  int tid = threadIdx.x;
  int wv = tid >> 6, lane = tid & 63;
  int l15 = lane & 15, lg = lane >> 4;
  int pw = (wv >> 1) * 64, ow = (wv & 1) * 64;
  f32x4 acc[4][4];
#pragma unroll
  for (int i = 0; i < 4; ++i)
#pragma unroll
    for (int j = 0; j < 4; ++j) acc[i][j] = 0.f;
  const float* Xb = X + (size_t)bb * 384 * 36864;
  int arow = tid >> 1, ahalf = tid & 1;
  int bp = tid & 127, bcg0 = tid >> 7;
  for (int ks = 0; ks < 12; ++ks) {
    int c0 = ks * 32;
    __syncthreads();
    {  // stage W tile: 128 o x 32 c
      const uint4* s4 = (const uint4*)(W + (size_t)(obase + arow) * 384 + c0 + ahalf * 16);
      uint4 a0 = s4[0], a1 = s4[1];
      uint4* d = (uint4*)&As[arow * 40 + ahalf * 16];
      d[0] = a0; d[1] = a1;
    }
    {  // stage X tile: 128 p x 32 c, fp32->bf16, transpose
#pragma unroll
      for (int q = 0; q < 2; ++q) {
        int cg = bcg0 + q * 2;
        int cc = c0 + cg * 8;
        const float* src = Xb + (size_t)cc * 36864 + pbase + bp;
        ushort8 t8;
#pragma unroll
        for (int j = 0; j < 8; ++j) t8[j] = f2bf(src[(size_t)j * 36864]);
        *(ushort8*)&Bs[bp * 40 + cg * 8] = t8;
      }
    }
    __syncthreads();
    short8 af[4], bf[4];
#pragma unroll
    for (int f = 0; f < 4; ++f) af[f] = *(const short8*)&Bs[(pw + f * 16 + l15) * 40 + lg * 8];
#pragma unroll
    for (int f = 0; f < 4; ++f) bf[f] = *(const short8*)&As[(ow + f * 16 + l15) * 40 + lg * 8];
#pragma unroll
    for (int fm = 0; fm < 4; ++fm)
#pragma unroll
      for (int fn = 0; fn < 4; ++fn)
        acc[fm][fn] = MFMA(af[fm], bf[fn], acc[fm][fn]);
  }
  unsigned short* Ob = Out + (size_t)bb * 36864 * OW;
#pragma unroll
  for (int fn = 0; fn < 4; ++fn) {
    int o = obase + ow + fn * 16 + l15;
    float bsv = bias[o];
#pragma unroll
    for (int fm = 0; fm < 4; ++fm) {
#pragma unroll
      for (int r = 0; r < 4; ++r) {
        int p = pbase + pw + fm * 16 + lg * 4 + r;
        Ob[(size_t)p * OW + o] = f2bf(acc[fm][fn][r] + bsv);
      }
    }
  }
}

// ---------------- windowed attention (flash-style), MODE 0/1/2 -------------
// MODE0: S=16, 4 windows/block (1/wave). MODE1: S=64, 1 window. MODE2: S=256,
// block = (window, query-tile of 64), 4 KV tiles with online softmax.
// x (= attn+residual, bf16) overwrites the q-region of the qv buffer.
template <int MODE>
__launch_bounds__(256)
__global__ void attn_kernel(const unsigned short* qv, const unsigned short* kx,
                            const float* __restrict__ rgb, unsigned short* xout) {
  constexpr int GB = MODE * 128;
  constexpr int NKV = (MODE == 2) ? 4 : 1;
  constexpr int NKF = (MODE == 0) ? 1 : 4;
  int bi = blockIdx.x;
  int bb = bi / 576;
  int r5 = bi % 576;
  int tid = threadIdx.x;
  int wv = tid >> 6, lane = tid & 63;
  int l15 = lane & 15, lg = lane >> 4;

  int h0, w0, qtb;
  if (MODE == 0) { int wy = r5 / 12; int wxb = (r5 % 12) * 4; h0 = wy * 4; w0 = wxb * 4; qtb = 0; }
  else if (MODE == 1) { int wy = r5 / 24; int wx = r5 % 24; h0 = wy * 8; w0 = wx * 8; qtb = 0; }
  else { int win = r5 >> 2; int qt = r5 & 3; int wy = win / 12; int wx = win % 12; h0 = wy * 16; w0 = wx * 16; qtb = qt * 64; }

  auto tok2p = [&](int t) -> int {
    if (MODE == 0) { int lw = t >> 4, tt = t & 15; return (h0 + (tt >> 2)) * 192 + w0 + lw * 4 + (tt & 3); }
    else if (MODE == 1) { return (h0 + (t >> 3)) * 192 + w0 + (t & 7); }
    else { return (h0 + (t >> 4)) * 192 + w0 + (t & 15); }
  };

  __shared__ unsigned short Qs[64 * 128];   // [tok][c] xor-swizzled
  __shared__ unsigned short Ks[64 * 128];   // [key][c] xor-swizzled
  __shared__ unsigned short Vst[128 * 64];  // [c][key] vswz
  __shared__ unsigned short Ps[4 * 16 * 72];

  const unsigned short* qvB = qv + (size_t)bb * 36864 * 768;
  const unsigned short* kB = kx + (size_t)bb * 36864 * 384;

  // stage Q (64 tokens x 128 c)
  for (int ch = tid; ch < 1024; ch += 256) {
    int tok = ch >> 4, c8 = (ch & 15) << 3;
    int p = tok2p(qtb + tok);
    uint4 v = *(const uint4*)(qvB + (size_t)p * 768 + GB + c8);
    *(uint4*)&Qs[tok * 128 + (c8 ^ ((tok & 7) << 3))] = v;
  }
  __syncthreads();
  short8 qf[4];
  {
    int qrow = wv * 16 + l15;
#pragma unroll
    for (int cs = 0; cs < 4; ++cs)
      qf[cs] = *(const short8*)&Qs[qrow * 128 + ((cs * 32 + lg * 8) ^ ((qrow & 7) << 3))];
  }

  float m[4], s[4];
#pragma unroll
  for (int r = 0; r < 4; ++r) { m[r] = -1e30f; s[r] = 0.f; }
  f32x4 oacc[8];
#pragma unroll
  for (int i = 0; i < 8; ++i) oacc[i] = 0.f;

  for (int kt = 0; kt < NKV; ++kt) {
    __syncthreads();  // previous tile consumed by all waves
    for (int ch = tid; ch < 1024; ch += 256) {  // stage K tile
      int tok = ch >> 4, c8 = (ch & 15) << 3;
      int p = tok2p(kt * 64 + tok);
      uint4 v = *(const uint4*)(kB + (size_t)p * 384 + GB + c8);
      *(uint4*)&Ks[tok * 128 + (c8 ^ ((tok & 7) << 3))] = v;
    }
    for (int ch = tid; ch < 1024; ch += 256) {  // stage V tile (transposed)
      int key = ch >> 4, c8 = (ch & 15) << 3;
      int p = tok2p(kt * 64 + key);
      ushort8 v = *(const ushort8*)(qvB + (size_t)p * 768 + 384 + GB + c8);
#pragma unroll
      for (int j = 0; j < 8; ++j)
        Vst[(c8 + j) * 64 + vswz(c8 + j, key)] = v[j];
    }
    __syncthreads();

    // QK^T: wave computes 16 queries x (NKF*16) keys
    f32x4 sc[NKF];
#pragma unroll
    for (int kfi = 0; kfi < NKF; ++kfi) {
      int kf = (MODE == 0) ? wv : kfi;
      int krow = kf * 16 + l15;
      f32x4 a; a = 0.f;
#pragma unroll
      for (int cs = 0; cs < 4; ++cs) {
        short8 kfr = *(const short8*)&Ks[krow * 128 + ((cs * 32 + lg * 8) ^ ((krow & 7) << 3))];
        a = MFMA(qf[cs], kfr, a);
      }
      sc[kfi] = a;
    }

    // online softmax (rows = queries lg*4+r, cols = keys l15 across lanes)
    unsigned short* Pw = Ps + wv * (16 * 72);
    float pr[4][NKF];
#pragma unroll
    for (int r = 0; r < 4; ++r) {
      float mx = -1e30f;
#pragma unroll
      for (int kfi = 0; kfi < NKF; ++kfi) mx = fmaxf(mx, sc[kfi][r]);
#pragma unroll
      for (int d = 1; d < 16; d <<= 1) mx = fmaxf(mx, __shfl_xor(mx, d));
      float mn = fmaxf(m[r], mx);
      float f = __expf(m[r] - mn);
      float ls = 0.f;
#pragma unroll
      for (int kfi = 0; kfi < NKF; ++kfi) { float e = __expf(sc[kfi][r] - mn); pr[r][kfi] = e; ls += e; }
#pragma unroll
      for (int d = 1; d < 16; d <<= 1) ls += __shfl_xor(ls, d);
      s[r] = s[r] * f + ls;
      m[r] = mn;
#pragma unroll
      for (int ct = 0; ct < 8; ++ct) oacc[ct][r] *= f;
    }
    // write P (bf16) to per-wave LDS
#pragma unroll
    for (int r = 0; r < 4; ++r) {
      int prow = lg * 4 + r;
#pragma unroll
      for (int kfi = 0; kfi < NKF; ++kfi) {
        int pcol = (MODE == 0) ? l15 : kfi * 16 + l15;
        Pw[prow * 72 + pcol] = f2bf(pr[r][kfi]);
      }
      if (MODE == 0) Pw[prow * 72 + 16 + l15] = 0;
    }
    // PV
    constexpr int nks = (MODE == 0) ? 1 : 2;
#pragma unroll
    for (int ks = 0; ks < nks; ++ks) {
      short8 pf = *(const short8*)&Pw[l15 * 72 + ks * 32 + lg * 8];
#pragma unroll
      for (int ct = 0; ct < 8; ++ct) {
        int c = ct * 16 + l15;
        short8 vf;
        if (MODE == 0) {
          if (lg < 2) vf = *(const short8*)&Vst[c * 64 + vswz(c, wv * 16 + lg * 8)];
          else vf = 0;
        } else {
          vf = *(const short8*)&Vst[c * 64 + vswz(c, ks * 32 + lg * 8)];
        }
        oacc[ct] = MFMA(pf, vf, oacc[ct]);
      }
    }
  }

  // epilogue: divide by sum, add residual, store x (bf16, NHWC into q-region)
  const float* rgbB = rgb + (size_t)bb * 384 * 36864;
  unsigned short* xB = xout + (size_t)bb * 36864 * 768;
#pragma unroll
  for (int r = 0; r < 4; ++r) {
    int q64 = wv * 16 + lg * 4 + r;
    int p = tok2p(qtb + q64);
    float inv = 1.0f / s[r];
#pragma unroll
    for (int ct = 0; ct < 8; ++ct) {
      int c = GB + ct * 16 + l15;
      float val = oacc[ct][r] * inv + rgbB[(size_t)c * 36864 + p];
      xB[(size_t)p * 768 + c] = f2bf(val);
    }
  }
}

// ---------------- 3x3 conv (implicit GEMM) + BN + LeakyReLU ----------------
__launch_bounds__(256)
__global__ void conv3_kernel(const unsigned short* __restrict__ X,  // qv buffer rows of 768, ch [0,384)
                             const unsigned short* __restrict__ Wc,
                             const float* __restrict__ s_oc, const float* __restrict__ t_oc,
                             float* __restrict__ Out) {
  int bi = blockIdx.x;
  int pt = bi % 288;
  int ot = (bi / 288) % 3;
  int bb = bi / 864;
  int obase = ot * 128, pbase = pt * 128;
  __shared__ unsigned short As[128 * 40];
  __shared__ unsigned short Bs[128 * 40];
  int tid = threadIdx.x;
  int wv = tid >> 6, lane = tid & 63;
  int l15 = lane & 15, lg = lane >> 4;
  int ow = (wv & 1) * 64, pw = (wv >> 1) * 64;
  f32x4 acc[4][4];
#pragma unroll
  for (int i = 0; i < 4; ++i)
#pragma unroll
    for (int j = 0; j < 4; ++j) acc[i][j] = 0.f;
  int arow = tid >> 1, ahalf = tid & 1;
  int sp = pbase + arow;
  int sh = sp / 192, sw = sp % 192;
  const unsigned short* Xb = X + (size_t)bb * 36864 * 768;
  for (int ksi = 0; ksi < 108; ++ksi) {
    int kq = ksi / 12;
    int c0 = (ksi % 12) * 32;
    int dh = kq / 3 - 1, dw = kq % 3 - 1;
    __syncthreads();
    {  // W tile
      const uint4* s4 = (const uint4*)(Wc + (size_t)(obase + arow) * 3456 + kq * 384 + c0 + ahalf * 16);
      uint4 a0 = s4[0], a1 = s4[1];
      uint4* d = (uint4*)&As[arow * 40 + ahalf * 16];
      d[0] = a0; d[1] = a1;
    }
    {  // im2col X tile with SAME-padding bounds check
      int hh = sh + dh, ww2 = sw + dw;
      uint4 b0 = {0, 0, 0, 0}, b1 = {0, 0, 0, 0};
      if ((unsigned)hh < 192u && (unsigned)ww2 < 192u) {
        const uint4* s4 = (const uint4*)(Xb + (size_t)(hh * 192 + ww2) * 768 + c0 + ahalf * 16);
        b0 = s4[0]; b1 = s4[1];
      }
      uint4* d = (uint4*)&Bs[arow * 40 + ahalf * 16];
      d[0] = b0; d[1] = b1;
    }
    __syncthreads();
    short8 af[4], bf2[4];
#pragma unroll
    for (int f = 0; f < 4; ++f) af[f] = *(const short8*)&As[(ow + f * 16 + l15) * 40 + lg * 8];
#pragma unroll
    for (int f = 0; f < 4; ++f) bf2[f] = *(const short8*)&Bs[(pw + f * 16 + l15) * 40 + lg * 8];
#pragma unroll
    for (int fm = 0; fm < 4; ++fm)
#pragma unroll
      for (int fn = 0; fn < 4; ++fn)
        acc[fm][fn] = MFMA(af[fm], bf2[fn], acc[fm][fn]);
  }
  float* Ob = Out + (size_t)bb * 384 * 36864;
#pragma unroll
  for (int fm = 0; fm < 4; ++fm) {
#pragma unroll
    for (int r = 0; r < 4; ++r) {
      int o = obase + ow + fm * 16 + lg * 4 + r;
      float sv = s_oc[o], tv = t_oc[o];
#pragma unroll
      for (int fn = 0; fn < 4; ++fn) {
        int p = pbase + pw + fn * 16 + l15;
        float y = acc[fm][fn][r] * sv + tv;
        Ob[(size_t)o * 36864 + p] = (y >= 0.f) ? y : 0.2f * y;
      }
    }
  }
}

// ---------------- launch ----------------
extern "C" void kernel_launch(void* const* d_in, const int* in_sizes, int n_in,
                              void* d_out, int out_size, void* d_ws, size_t ws_size,
                              hipStream_t stream) {
  const float* rgb  = (const float*)d_in[0];
  const float* fre  = (const float*)d_in[1];
  const float* ng   = (const float*)d_in[2];
  const float* nb   = (const float*)d_in[3];
  const float* nm   = (const float*)d_in[4];
  const float* nv   = (const float*)d_in[5];
  const float* qv_w = (const float*)d_in[6];
  const float* qv_b = (const float*)d_in[7];
  const float* k_w  = (const float*)d_in[8];
  const float* k_b  = (const float*)d_in[9];
  const float* oc_w = (const float*)d_in[10];
  const float* oc_g = (const float*)d_in[11];
  const float* oc_b = (const float*)d_in[12];
  const float* oc_m = (const float*)d_in[13];
  const float* oc_v = (const float*)d_in[14];

  char* ws = (char*)d_ws;
  unsigned short* qvbuf = (unsigned short*)(ws);               // 147456*768*2 = 226492416
  unsigned short* kbuf  = (unsigned short*)(ws + 226492416);   // 147456*384*2 = 113246208
  unsigned short* Wq    = (unsigned short*)(ws + 339738624);   // 589824
  unsigned short* Wk    = (unsigned short*)(ws + 340328448);   // 294912
  unsigned short* Wc    = (unsigned short*)(ws + 340623360);   // 2654208
  float* bq  = (float*)(ws + 343277568);
  float* bk  = (float*)(ws + 343280640);
  float* soc = (float*)(ws + 343282176);
  float* toc = (float*)(ws + 343283712);
  float* out = (float*)d_out;

  fold_qvk_kernel<<<dim3(1152), dim3(128), 0, stream>>>(qv_w, qv_b, k_w, k_b, ng, nb, nm, nv, Wq, bq, Wk, bk);
  fold_oc_kernel<<<dim3(5184), dim3(256), 0, stream>>>(oc_w, oc_g, oc_b, oc_m, oc_v, Wc, soc, toc);
  gemm1_kernel<<<dim3(4 * 288 * 6), dim3(256), 0, stream>>>(rgb, Wq, bq, qvbuf, 768, 6);
  gemm1_kernel<<<dim3(4 * 288 * 3), dim3(256), 0, stream>>>(fre, Wk, bk, kbuf, 384, 3);
  attn_kernel<0><<<dim3(2304), dim3(256), 0, stream>>>(qvbuf, kbuf, rgb, qvbuf);
  attn_kernel<1><<<dim3(2304), dim3(256), 0, stream>>>(qvbuf, kbuf, rgb, qvbuf);
  attn_kernel<2><<<dim3(2304), dim3(256), 0, stream>>>(qvbuf, kbuf, rgb, qvbuf);
  conv3_kernel<<<dim3(4 * 3 * 288), dim3(256), 0, stream>>>(qvbuf, Wc, soc, toc, out);
}